// Round 9
// baseline (267.262 us; speedup 1.0000x reference)
//
#include <hip/hip_runtime.h>
#include <hip/hip_bf16.h>
#include <math.h>

#define NN 50000
#define NE 800000
#define DIM 128
#define NH 8
#define HD 16
#define NTILE 3125            // NN/16 exactly
#define TPB 782               // ceil(NTILE/4) tile-groups per matrix
#define LROW 136              // LDS row stride in shorts (128 + 8 pad)
#define QVROW 256             // interleaved qv row: 256 shorts = 512 B
#define SCAN_B 196            // ceil(NN/256)

typedef short v8s __attribute__((ext_vector_type(8)));
typedef float v4f __attribute__((ext_vector_type(4)));

__device__ __forceinline__ unsigned pack2(float a, float b) {
    __hip_bfloat162 h = __float22bfloat162_rn(make_float2(a, b));   // v_cvt_pk_bf16_f32
    return *reinterpret_cast<unsigned*>(&h);
}
__device__ __forceinline__ float blo(unsigned w) { return __uint_as_float(w << 16); }
__device__ __forceinline__ float bhi(unsigned w) { return __uint_as_float(w & 0xffff0000u); }

// ---- stage one 128x128 fp32 matrix into LDS as bf16 (padded rows) ----
__device__ __forceinline__ void stage_w_lds(
    const float* __restrict__ Wg, unsigned short* __restrict__ Wl, int tid)
{
#pragma unroll
    for (int it = 0; it < 16; ++it) {
        int chunk = it * 256 + tid;          // 0..4095 float4 chunks
        int row = chunk >> 5, c4 = chunk & 31;
        float4 f = ((const float4*)Wg)[chunk];
        uint2 o = { pack2(f.x, f.y), pack2(f.z, f.w) };
        *(uint2*)(Wl + row * LROW + c4 * 4) = o;
    }
}

// ---- K1: QKV via MFMA (+ folded edge histogram). A=W, B=x (swapped):
// D: node = lane&15, outcol = nt*16 + quad*4 + reg  -> packed dword stores.
__global__ __launch_bounds__(256) void qkv_mfma_kernel(
    const float* __restrict__ x,
    const float* __restrict__ Wq, const float* __restrict__ Wk, const float* __restrict__ Wv,
    const float* __restrict__ bq, const float* __restrict__ bk, const float* __restrict__ bv,
    unsigned short* __restrict__ qvb, unsigned short* __restrict__ kb,
    const int* __restrict__ tgt, int* __restrict__ cnt)
{
    __shared__ unsigned short Wl[DIM * LROW];   // 34816 B
    const int mat = blockIdx.x / TPB;           // 0=q, 1=k, 2=v
    const int tg  = blockIdx.x % TPB;
    const int tid = threadIdx.x;
    const int lane = tid & 63;
    const int warp = tid >> 6;
    const int m = lane & 15;
    const int quad = lane >> 4;

    // folded histogram: grid-stride over edges (fire-and-forget atomics)
    const int gsize = 3 * TPB * 256;
    for (int e = blockIdx.x * 256 + tid; e < NE; e += gsize)
        atomicAdd(cnt + tgt[e], 1);

    const float* Wg = (mat == 0) ? Wq : (mat == 1) ? Wk : Wv;
    stage_w_lds(Wg, Wl, tid);
    __syncthreads();

    const int rt = tg * 4 + warp;
    if (rt >= NTILE) return;
    const int r0 = rt * 16;
    const int node = r0 + m;

    const float* bias_p = (mat == 0) ? bq : (mat == 1) ? bk : bv;

    // x fragment (B operand): row r0+m, k = kt*32 + quad*8 + (0..7)
    v8s a[4];
#pragma unroll
    for (int kt = 0; kt < 4; ++kt) {
        const float4* xr = (const float4*)(x + (size_t)node * DIM + kt * 32 + quad * 8);
        float4 f0 = xr[0], f1 = xr[1];
        uint4 u = { pack2(f0.x, f0.y), pack2(f0.z, f0.w),
                    pack2(f1.x, f1.y), pack2(f1.z, f1.w) };
        a[kt] = *(v8s*)&u;
    }

#pragma unroll
    for (int nt = 0; nt < 8; ++nt) {
        v4f c = {0.f, 0.f, 0.f, 0.f};
#pragma unroll
        for (int kt = 0; kt < 4; ++kt) {
            v8s wf = *(const v8s*)(Wl + (nt * 16 + m) * LROW + kt * 32 + quad * 8);
            c = __builtin_amdgcn_mfma_f32_16x16x32_bf16(wf, a[kt], c, 0, 0, 0);
        }
        const int cbase = nt * 16 + quad * 4;        // output col base (even)
        float4 b4 = *(const float4*)(bias_p + cbase);
        float o0 = c[0] + b4.x, o1 = c[1] + b4.y;
        float o2 = c[2] + b4.z, o3 = c[3] + b4.w;
        if (mat == 1) {
            uint2 pk = { pack2(o0, o1), pack2(o2, o3) };
            *(uint2*)(kb + (size_t)node * DIM + cbase) = pk;
        } else {
            // qv interleave: pair p -> q at shorts 4p..4p+1, v at 4p+2..4p+3
            int p0 = 2 * cbase + ((mat == 2) ? 2 : 0);
            *(unsigned*)(qvb + (size_t)node * QVROW + p0)     = pack2(o0, o1);
            *(unsigned*)(qvb + (size_t)node * QVROW + p0 + 4) = pack2(o2, o3);
        }
    }
}

// ---- K2: per-block (256-elem) local exclusive scan + block sums ----
__global__ __launch_bounds__(256) void scan1_kernel(
    const int* __restrict__ cnt, int* __restrict__ off, int* __restrict__ bsum)
{
    __shared__ int ws4[4];
    const int tid = threadIdx.x, lane = tid & 63, wid = tid >> 6;
    int i = blockIdx.x * 256 + tid;
    int v0 = (i < NN) ? cnt[i] : 0;
    int incl = v0;
#pragma unroll
    for (int d = 1; d < 64; d <<= 1) {
        int t = __shfl_up(incl, d);
        if (lane >= d) incl += t;
    }
    if (lane == 63) ws4[wid] = incl;
    __syncthreads();
    int wexcl = 0;
#pragma unroll
    for (int t = 0; t < 3; ++t) if (t < wid) wexcl += ws4[t];
    if (i < NN) off[i] = wexcl + incl - v0;
    if (tid == 255) bsum[blockIdx.x] = wexcl + incl;
}

// ---- K3: each block scans all 196 block sums, adds its base, inits cursor ----
__global__ __launch_bounds__(256) void scan23_kernel(
    const int* __restrict__ bsum, int* __restrict__ off, int* __restrict__ cursor)
{
    __shared__ int ws4[4];
    __shared__ int base_s, total_s;
    const int tid = threadIdx.x, lane = tid & 63, wid = tid >> 6;
    int v0 = (tid < SCAN_B) ? bsum[tid] : 0;
    int incl = v0;
#pragma unroll
    for (int d = 1; d < 64; d <<= 1) {
        int t = __shfl_up(incl, d);
        if (lane >= d) incl += t;
    }
    if (lane == 63) ws4[wid] = incl;
    __syncthreads();
    int wexcl = 0;
#pragma unroll
    for (int t = 0; t < 3; ++t) if (t < wid) wexcl += ws4[t];
    int excl = wexcl + incl - v0;
    if (tid == blockIdx.x) base_s = excl;
    if (tid == SCAN_B - 1) total_s = excl + v0;
    __syncthreads();
    int i = blockIdx.x * 256 + tid;
    if (i < NN) {
        int t = off[i] + base_s;
        off[i] = t;
        cursor[i] = t;
    }
    if (blockIdx.x == SCAN_B - 1 && tid == 0) off[NN] = total_s;
}

// ---- K4: fill CSR (src only; tgt implicit in bucket) ----
__global__ __launch_bounds__(256) void fill_kernel(
    const int* __restrict__ tgt, const int* __restrict__ src,
    int* __restrict__ cursor, int* __restrict__ edge_src)
{
    int e = blockIdx.x * 256 + threadIdx.x;
    if (e >= NE) return;
    int t = tgt[e];
    int pos = atomicAdd(cursor + t, 1);
    edge_src[pos] = src[e];
}

// ---- K5: fused attention, 2 waves per node, batch-8 MLP + tree reduce. ----
__global__ __launch_bounds__(256) void attn_kernel(
    const int* __restrict__ off, const int* __restrict__ edge_src,
    const unsigned short* __restrict__ qvb, const unsigned short* __restrict__ kb,
    unsigned short* __restrict__ aggb)
{
    __shared__ float red[2][64][3];
    const int tid = threadIdx.x;
    const int nib = tid >> 7;            // node-in-block (0..1)
    const int w   = (tid >> 6) & 1;      // wave half: even/odd edges
    const int lane = tid & 63;
    const int node = blockIdx.x * 2 + nib;

    const int base = off[node];
    const int deg  = off[node + 1] - base;

    unsigned kw = *(const unsigned*)(kb + (size_t)node * DIM + 2 * lane);
    const float klo = blo(kw), khi = bhi(kw);

    const int j = lane & 7;
    const int gb = lane & 56;            // 8-lane group base

    float ax = 0.f, ay = 0.f, ss = 0.f;
    const int nw = (deg + 1 - w) >> 1;   // edges for this wave: 2*i+w
    for (int c0 = 0; c0 < nw; c0 += 64) {
        int idx = c0 + lane;
        int srcv = edge_src[base + min(2 * idx + w, deg - 1)];
        int nchunk = min(nw - c0, 64);
        for (int b = 0; b < nchunk; b += 8) {
            int nb = min(nchunk - b, 8);
            uint2 qv[8];
#pragma unroll
            for (int i = 0; i < 8; ++i) {
                int si = __shfl(srcv, b + min(i, nb - 1));
                qv[i] = *(const uint2*)(qvb + (size_t)si * QVROW + 4 * lane);
            }
            float part[8];
#pragma unroll
            for (int i = 0; i < 8; ++i)
                part[i] = blo(qv[i].x) * klo + bhi(qv[i].x) * khi;
            float r1[4];
#pragma unroll
            for (int t = 0; t < 4; ++t) {
                float keep = (j & 1) ? part[2 * t + 1] : part[2 * t];
                float send = (j & 1) ? part[2 * t]     : part[2 * t + 1];
                r1[t] = keep + __shfl_xor(send, 1);
            }
            float r2[2];
#pragma unroll
            for (int u = 0; u < 2; ++u) {
                float keep = (j & 2) ? r1[2 * u + 1] : r1[2 * u];
                float send = (j & 2) ? r1[2 * u]     : r1[2 * u + 1];
                r2[u] = keep + __shfl_xor(send, 2);
            }
            float keep = (j & 4) ? r2[1] : r2[0];
            float send = (j & 4) ? r2[0] : r2[1];
            float tot = keep + __shfl_xor(send, 4);
            float p = __expf(tot * 0.25f);   // 1/sqrt(HD)
#pragma unroll
            for (int i = 0; i < 8; ++i) {
                if (i < nb) {
                    float pi = __shfl(p, gb + i);
                    unsigned vv = qv[i].y;
                    ax += pi * blo(vv);
                    ay += pi * bhi(vv);
                    ss += pi;
                }
            }
        }
    }
    if (w == 1) {
        red[nib][lane][0] = ax; red[nib][lane][1] = ay; red[nib][lane][2] = ss;
    }
    __syncthreads();
    if (w == 0) {
        ax += red[nib][lane][0]; ay += red[nib][lane][1]; ss += red[nib][lane][2];
        unsigned* ap = (unsigned*)(aggb + (size_t)node * DIM + 2 * lane);
        if (deg == 0) {
            *ap = 0u;
        } else {
            float inv = 1.f / ss;
            *ap = pack2(ax * inv, ay * inv);
        }
    }
}

// ---- K6: out = agg @ Wo.T + bo via MFMA, A=Wo, B=agg, float4 stores ----
__global__ __launch_bounds__(256) void outproj_mfma_kernel(
    const unsigned short* __restrict__ aggb, const float* __restrict__ Wo,
    const float* __restrict__ bo, float* __restrict__ out)
{
    __shared__ unsigned short Wl[DIM * LROW];
    const int tid = threadIdx.x;
    const int lane = tid & 63;
    const int warp = tid >> 6;
    const int m = lane & 15;
    const int quad = lane >> 4;

    stage_w_lds(Wo, Wl, tid);
    __syncthreads();

    const int rt = blockIdx.x * 4 + warp;
    if (rt >= NTILE) return;
    const int r0 = rt * 16;
    const int node = r0 + m;

    v8s a[4];
#pragma unroll
    for (int kt = 0; kt < 4; ++kt)
        a[kt] = *(const v8s*)(aggb + (size_t)node * DIM + kt * 32 + quad * 8);

#pragma unroll
    for (int nt = 0; nt < 8; ++nt) {
        v4f c = {0.f, 0.f, 0.f, 0.f};
#pragma unroll
        for (int kt = 0; kt < 4; ++kt) {
            v8s wf = *(const v8s*)(Wl + (nt * 16 + m) * LROW + kt * 32 + quad * 8);
            c = __builtin_amdgcn_mfma_f32_16x16x32_bf16(wf, a[kt], c, 0, 0, 0);
        }
        const int cbase = nt * 16 + quad * 4;
        float4 b4 = *(const float4*)(bo + cbase);
        float4 o = { c[0] + b4.x, c[1] + b4.y, c[2] + b4.z, c[3] + b4.w };
        *(float4*)(out + (size_t)node * DIM + cbase) = o;
    }
}

extern "C" void kernel_launch(void* const* d_in, const int* in_sizes, int n_in,
                              void* d_out, int out_size, void* d_ws, size_t ws_size,
                              hipStream_t stream) {
    const float* x  = (const float*)d_in[0];
    const int*   ei = (const int*)d_in[1];      // [2, NE]: row0 = tgt, row1 = src
    const float* Wq = (const float*)d_in[2];
    const float* bq = (const float*)d_in[3];
    const float* Wk = (const float*)d_in[4];
    const float* bk = (const float*)d_in[5];
    const float* Wv = (const float*)d_in[6];
    const float* bv = (const float*)d_in[7];
    const float* Wo = (const float*)d_in[8];
    const float* bo = (const float*)d_in[9];

    const int* tgt = ei;
    const int* src = ei + NE;

    char* ws = (char*)d_ws;
    const size_t SZ_QV = (size_t)NN * QVROW * 2;    // 25.6 MB interleaved q+v
    const size_t SZ_BF = (size_t)NN * DIM * 2;      // 12.8 MB

    unsigned short* qvb  = (unsigned short*)(ws);
    unsigned short* kb   = (unsigned short*)(ws + SZ_QV);
    unsigned short* aggb = (unsigned short*)(ws + SZ_QV + SZ_BF);

    char* wi = ws + SZ_QV + 2 * SZ_BF;
    int* cnt      = (int*)(wi);
    int* off      = (int*)(wi + (size_t)NN * 4);
    int* cursor   = (int*)(wi + (size_t)(2 * NN + 1) * 4);
    int* edge_src = (int*)(wi + (size_t)(3 * NN + 1) * 4);
    int* bsum     = (int*)(wi + (size_t)(3 * NN + 1) * 4 + (size_t)NE * 4);

    const int edge_blocks = (NE + 255) / 256;  // 3125

    hipMemsetAsync(cnt, 0, (size_t)NN * 4, stream);
    qkv_mfma_kernel<<<3 * TPB, 256, 0, stream>>>(
        x, Wq, Wk, Wv, bq, bk, bv, qvb, kb, tgt, cnt);
    scan1_kernel<<<SCAN_B, 256, 0, stream>>>(cnt, off, bsum);
    scan23_kernel<<<SCAN_B, 256, 0, stream>>>(bsum, off, cursor);
    fill_kernel<<<edge_blocks, 256, 0, stream>>>(tgt, src, cursor, edge_src);
    attn_kernel<<<(NN + 1) / 2, 256, 0, stream>>>(off, edge_src, qvb, kb, aggb);
    outproj_mfma_kernel<<<TPB, 256, 0, stream>>>(aggb, Wo, bo, (float*)d_out);
}

// Round 10
// 258.837 us; speedup vs baseline: 1.0326x; 1.0326x over previous
//
#include <hip/hip_runtime.h>
#include <hip/hip_bf16.h>
#include <math.h>

#define NN 50000
#define NE 800000
#define DIM 128
#define NH 8
#define HD 16
#define NTILE 3125            // NN/16 exactly
#define TPB 782               // ceil(NTILE/4) blocks (4 row-tiles per block)
#define LROW 136              // LDS row stride in shorts (128 + 8 pad)
#define QVROW 256             // interleaved qv row: 256 shorts = 512 B
#define SCAN_B 196            // ceil(NN/256)

typedef short v8s __attribute__((ext_vector_type(8)));
typedef float v4f __attribute__((ext_vector_type(4)));

__device__ __forceinline__ unsigned pack2(float a, float b) {
    __hip_bfloat162 h = __float22bfloat162_rn(make_float2(a, b));   // v_cvt_pk_bf16_f32
    return *reinterpret_cast<unsigned*>(&h);
}
__device__ __forceinline__ float blo(unsigned w) { return __uint_as_float(w << 16); }
__device__ __forceinline__ float bhi(unsigned w) { return __uint_as_float(w & 0xffff0000u); }

// ---- stage one 128x128 fp32 matrix into LDS as bf16, b128 writes
// (the R5-R7 pattern measured at 0 bank conflicts), fp32->bf16 in flight ----
__device__ __forceinline__ void stage_w_lds(
    const float* __restrict__ Wg, unsigned short* __restrict__ Wl, int tid)
{
#pragma unroll
    for (int it = 0; it < 8; ++it) {
        int chunk = it * 256 + tid;          // 0..2047 chunks of 8 shorts
        int row = chunk >> 4, c8 = chunk & 15;
        float4 f0 = ((const float4*)Wg)[2 * chunk];
        float4 f1 = ((const float4*)Wg)[2 * chunk + 1];
        uint4 o = { pack2(f0.x, f0.y), pack2(f0.z, f0.w),
                    pack2(f1.x, f1.y), pack2(f1.z, f1.w) };
        *(uint4*)(Wl + row * LROW + c8 * 8) = o;
    }
}

// ---- K1: fused QKV via MFMA (+ folded edge histogram).
// One block = 4 row-tiles; stages Wq -> Wv -> Wk serially in one LDS buffer.
// Operands swapped (A=W, B=x): D gives node=lane&15, cols=nt*16+quad*4+reg,
// so each lane emits packed full-sector stores (uint4 for qv, uint2 for k).
__global__ __launch_bounds__(256) void qkv_mfma_kernel(
    const float* __restrict__ x,
    const float* __restrict__ Wq, const float* __restrict__ Wk, const float* __restrict__ Wv,
    const float* __restrict__ bq, const float* __restrict__ bk, const float* __restrict__ bv,
    unsigned short* __restrict__ qvb, unsigned short* __restrict__ kb,
    const int* __restrict__ tgt, int* __restrict__ cnt)
{
    __shared__ unsigned short Wl[DIM * LROW];   // 34816 B
    const int tid = threadIdx.x;
    const int lane = tid & 63;
    const int warp = tid >> 6;
    const int m = lane & 15;
    const int quad = lane >> 4;

    // folded histogram: grid-stride over edges (fire-and-forget atomics)
    const int gsize = TPB * 256;
    for (int e = blockIdx.x * 256 + tid; e < NE; e += gsize)
        atomicAdd(cnt + tgt[e], 1);

    const int rt = blockIdx.x * 4 + warp;
    const bool active = (rt < NTILE);
    const int node = (active ? rt : 0) * 16 + m;

    // x fragment (B operand): row node, k = kt*32 + quad*8 + (0..7)
    v8s a[4];
    if (active) {
#pragma unroll
        for (int kt = 0; kt < 4; ++kt) {
            const float4* xr = (const float4*)(x + (size_t)node * DIM + kt * 32 + quad * 8);
            float4 f0 = xr[0], f1 = xr[1];
            uint4 u = { pack2(f0.x, f0.y), pack2(f0.z, f0.w),
                        pack2(f1.x, f1.y), pack2(f1.z, f1.w) };
            a[kt] = *(v8s*)&u;
        }
    }

    // ---- Q ----
    stage_w_lds(Wq, Wl, tid);
    __syncthreads();
    uint2 uq[8];
    if (active) {
#pragma unroll
        for (int nt = 0; nt < 8; ++nt) {
            v4f c = {0.f, 0.f, 0.f, 0.f};
#pragma unroll
            for (int kt = 0; kt < 4; ++kt) {
                v8s wf = *(const v8s*)(Wl + (nt * 16 + m) * LROW + kt * 32 + quad * 8);
                c = __builtin_amdgcn_mfma_f32_16x16x32_bf16(wf, a[kt], c, 0, 0, 0);
            }
            int cbase = nt * 16 + quad * 4;
            float4 b4 = *(const float4*)(bq + cbase);
            uq[nt].x = pack2(c[0] + b4.x, c[1] + b4.y);
            uq[nt].y = pack2(c[2] + b4.z, c[3] + b4.w);
        }
    }
    __syncthreads();

    // ---- V (combine with held Q -> full uint4 stores) ----
    stage_w_lds(Wv, Wl, tid);
    __syncthreads();
    if (active) {
#pragma unroll
        for (int nt = 0; nt < 8; ++nt) {
            v4f c = {0.f, 0.f, 0.f, 0.f};
#pragma unroll
            for (int kt = 0; kt < 4; ++kt) {
                v8s wf = *(const v8s*)(Wl + (nt * 16 + m) * LROW + kt * 32 + quad * 8);
                c = __builtin_amdgcn_mfma_f32_16x16x32_bf16(wf, a[kt], c, 0, 0, 0);
            }
            int cbase = nt * 16 + quad * 4;
            float4 b4 = *(const float4*)(bv + cbase);
            unsigned v01 = pack2(c[0] + b4.x, c[1] + b4.y);
            unsigned v23 = pack2(c[2] + b4.z, c[3] + b4.w);
            // qv layout: pair p -> shorts 4p..4p+3 = {q2p,q2p+1,v2p,v2p+1}
            uint4 st = { uq[nt].x, v01, uq[nt].y, v23 };
            *(uint4*)(qvb + (size_t)node * QVROW + 2 * cbase) = st;
        }
    }
    __syncthreads();

    // ---- K ----
    stage_w_lds(Wk, Wl, tid);
    __syncthreads();
    if (active) {
#pragma unroll
        for (int nt = 0; nt < 8; ++nt) {
            v4f c = {0.f, 0.f, 0.f, 0.f};
#pragma unroll
            for (int kt = 0; kt < 4; ++kt) {
                v8s wf = *(const v8s*)(Wl + (nt * 16 + m) * LROW + kt * 32 + quad * 8);
                c = __builtin_amdgcn_mfma_f32_16x16x32_bf16(wf, a[kt], c, 0, 0, 0);
            }
            int cbase = nt * 16 + quad * 4;
            float4 b4 = *(const float4*)(bk + cbase);
            uint2 pk = { pack2(c[0] + b4.x, c[1] + b4.y),
                         pack2(c[2] + b4.z, c[3] + b4.w) };
            *(uint2*)(kb + (size_t)node * DIM + cbase) = pk;
        }
    }
}

// ---- K2: per-block (256-elem) local exclusive scan + block sums ----
__global__ __launch_bounds__(256) void scan1_kernel(
    const int* __restrict__ cnt, int* __restrict__ off, int* __restrict__ bsum)
{
    __shared__ int ws4[4];
    const int tid = threadIdx.x, lane = tid & 63, wid = tid >> 6;
    int i = blockIdx.x * 256 + tid;
    int v0 = (i < NN) ? cnt[i] : 0;
    int incl = v0;
#pragma unroll
    for (int d = 1; d < 64; d <<= 1) {
        int t = __shfl_up(incl, d);
        if (lane >= d) incl += t;
    }
    if (lane == 63) ws4[wid] = incl;
    __syncthreads();
    int wexcl = 0;
#pragma unroll
    for (int t = 0; t < 3; ++t) if (t < wid) wexcl += ws4[t];
    if (i < NN) off[i] = wexcl + incl - v0;
    if (tid == 255) bsum[blockIdx.x] = wexcl + incl;
}

// ---- K3: each block scans all 196 block sums, adds its base, inits cursor ----
__global__ __launch_bounds__(256) void scan23_kernel(
    const int* __restrict__ bsum, int* __restrict__ off, int* __restrict__ cursor)
{
    __shared__ int ws4[4];
    __shared__ int base_s, total_s;
    const int tid = threadIdx.x, lane = tid & 63, wid = tid >> 6;
    int v0 = (tid < SCAN_B) ? bsum[tid] : 0;
    int incl = v0;
#pragma unroll
    for (int d = 1; d < 64; d <<= 1) {
        int t = __shfl_up(incl, d);
        if (lane >= d) incl += t;
    }
    if (lane == 63) ws4[wid] = incl;
    __syncthreads();
    int wexcl = 0;
#pragma unroll
    for (int t = 0; t < 3; ++t) if (t < wid) wexcl += ws4[t];
    int excl = wexcl + incl - v0;
    if (tid == blockIdx.x) base_s = excl;
    if (tid == SCAN_B - 1) total_s = excl + v0;
    __syncthreads();
    int i = blockIdx.x * 256 + tid;
    if (i < NN) {
        int t = off[i] + base_s;
        off[i] = t;
        cursor[i] = t;
    }
    if (blockIdx.x == SCAN_B - 1 && tid == 0) off[NN] = total_s;
}

// ---- K4: fill CSR (src only; tgt implicit in bucket) ----
__global__ __launch_bounds__(256) void fill_kernel(
    const int* __restrict__ tgt, const int* __restrict__ src,
    int* __restrict__ cursor, int* __restrict__ edge_src)
{
    int e = blockIdx.x * 256 + threadIdx.x;
    if (e >= NE) return;
    int t = tgt[e];
    int pos = atomicAdd(cursor + t, 1);
    edge_src[pos] = src[e];
}

// ---- K5: fused attention, 2 waves per node, batch-8 MLP + tree reduce. ----
__global__ __launch_bounds__(256) void attn_kernel(
    const int* __restrict__ off, const int* __restrict__ edge_src,
    const unsigned short* __restrict__ qvb, const unsigned short* __restrict__ kb,
    unsigned short* __restrict__ aggb)
{
    __shared__ float red[2][64][3];
    const int tid = threadIdx.x;
    const int nib = tid >> 7;            // node-in-block (0..1)
    const int w   = (tid >> 6) & 1;      // wave half: even/odd edges
    const int lane = tid & 63;
    const int node = blockIdx.x * 2 + nib;

    const int base = off[node];
    const int deg  = off[node + 1] - base;

    unsigned kw = *(const unsigned*)(kb + (size_t)node * DIM + 2 * lane);
    const float klo = blo(kw), khi = bhi(kw);

    const int j = lane & 7;
    const int gb = lane & 56;            // 8-lane group base

    float ax = 0.f, ay = 0.f, ss = 0.f;
    const int nw = (deg + 1 - w) >> 1;   // edges for this wave: 2*i+w
    for (int c0 = 0; c0 < nw; c0 += 64) {
        int idx = c0 + lane;
        int srcv = edge_src[base + min(2 * idx + w, deg - 1)];
        int nchunk = min(nw - c0, 64);
        for (int b = 0; b < nchunk; b += 8) {
            int nb = min(nchunk - b, 8);
            uint2 qv[8];
#pragma unroll
            for (int i = 0; i < 8; ++i) {
                int si = __shfl(srcv, b + min(i, nb - 1));
                qv[i] = *(const uint2*)(qvb + (size_t)si * QVROW + 4 * lane);
            }
            float part[8];
#pragma unroll
            for (int i = 0; i < 8; ++i)
                part[i] = blo(qv[i].x) * klo + bhi(qv[i].x) * khi;
            float r1[4];
#pragma unroll
            for (int t = 0; t < 4; ++t) {
                float keep = (j & 1) ? part[2 * t + 1] : part[2 * t];
                float send = (j & 1) ? part[2 * t]     : part[2 * t + 1];
                r1[t] = keep + __shfl_xor(send, 1);
            }
            float r2[2];
#pragma unroll
            for (int u = 0; u < 2; ++u) {
                float keep = (j & 2) ? r1[2 * u + 1] : r1[2 * u];
                float send = (j & 2) ? r1[2 * u]     : r1[2 * u + 1];
                r2[u] = keep + __shfl_xor(send, 2);
            }
            float keep = (j & 4) ? r2[1] : r2[0];
            float send = (j & 4) ? r2[0] : r2[1];
            float tot = keep + __shfl_xor(send, 4);
            float p = __expf(tot * 0.25f);   // 1/sqrt(HD)
#pragma unroll
            for (int i = 0; i < 8; ++i) {
                if (i < nb) {
                    float pi = __shfl(p, gb + i);
                    unsigned vv = qv[i].y;
                    ax += pi * blo(vv);
                    ay += pi * bhi(vv);
                    ss += pi;
                }
            }
        }
    }
    if (w == 1) {
        red[nib][lane][0] = ax; red[nib][lane][1] = ay; red[nib][lane][2] = ss;
    }
    __syncthreads();
    if (w == 0) {
        ax += red[nib][lane][0]; ay += red[nib][lane][1]; ss += red[nib][lane][2];
        unsigned* ap = (unsigned*)(aggb + (size_t)node * DIM + 2 * lane);
        if (deg == 0) {
            *ap = 0u;
        } else {
            float inv = 1.f / ss;
            *ap = pack2(ax * inv, ay * inv);
        }
    }
}

// ---- K6: out = agg @ Wo.T + bo via MFMA, A=Wo, B=agg, float4 stores ----
__global__ __launch_bounds__(256) void outproj_mfma_kernel(
    const unsigned short* __restrict__ aggb, const float* __restrict__ Wo,
    const float* __restrict__ bo, float* __restrict__ out)
{
    __shared__ unsigned short Wl[DIM * LROW];
    const int tid = threadIdx.x;
    const int lane = tid & 63;
    const int warp = tid >> 6;
    const int m = lane & 15;
    const int quad = lane >> 4;

    stage_w_lds(Wo, Wl, tid);

    const int rt = blockIdx.x * 4 + warp;
    const bool active = (rt < NTILE);
    const int node = (active ? rt : 0) * 16 + m;

    v8s a[4];
    if (active) {
#pragma unroll
        for (int kt = 0; kt < 4; ++kt)
            a[kt] = *(const v8s*)(aggb + (size_t)node * DIM + kt * 32 + quad * 8);
    }
    __syncthreads();
    if (!active) return;

#pragma unroll
    for (int nt = 0; nt < 8; ++nt) {
        v4f c = {0.f, 0.f, 0.f, 0.f};
#pragma unroll
        for (int kt = 0; kt < 4; ++kt) {
            v8s wf = *(const v8s*)(Wl + (nt * 16 + m) * LROW + kt * 32 + quad * 8);
            c = __builtin_amdgcn_mfma_f32_16x16x32_bf16(wf, a[kt], c, 0, 0, 0);
        }
        const int cbase = nt * 16 + quad * 4;
        float4 b4 = *(const float4*)(bo + cbase);
        float4 o = { c[0] + b4.x, c[1] + b4.y, c[2] + b4.z, c[3] + b4.w };
        *(float4*)(out + (size_t)node * DIM + cbase) = o;
    }
}

extern "C" void kernel_launch(void* const* d_in, const int* in_sizes, int n_in,
                              void* d_out, int out_size, void* d_ws, size_t ws_size,
                              hipStream_t stream) {
    const float* x  = (const float*)d_in[0];
    const int*   ei = (const int*)d_in[1];      // [2, NE]: row0 = tgt, row1 = src
    const float* Wq = (const float*)d_in[2];
    const float* bq = (const float*)d_in[3];
    const float* Wk = (const float*)d_in[4];
    const float* bk = (const float*)d_in[5];
    const float* Wv = (const float*)d_in[6];
    const float* bv = (const float*)d_in[7];
    const float* Wo = (const float*)d_in[8];
    const float* bo = (const float*)d_in[9];

    const int* tgt = ei;
    const int* src = ei + NE;

    char* ws = (char*)d_ws;
    const size_t SZ_QV = (size_t)NN * QVROW * 2;    // 25.6 MB interleaved q+v
    const size_t SZ_BF = (size_t)NN * DIM * 2;      // 12.8 MB

    unsigned short* qvb  = (unsigned short*)(ws);
    unsigned short* kb   = (unsigned short*)(ws + SZ_QV);
    unsigned short* aggb = (unsigned short*)(ws + SZ_QV + SZ_BF);

    char* wi = ws + SZ_QV + 2 * SZ_BF;
    int* cnt      = (int*)(wi);
    int* off      = (int*)(wi + (size_t)NN * 4);
    int* cursor   = (int*)(wi + (size_t)(2 * NN + 1) * 4);
    int* edge_src = (int*)(wi + (size_t)(3 * NN + 1) * 4);
    int* bsum     = (int*)(wi + (size_t)(3 * NN + 1) * 4 + (size_t)NE * 4);

    const int edge_blocks = (NE + 255) / 256;  // 3125

    hipMemsetAsync(cnt, 0, (size_t)NN * 4, stream);
    qkv_mfma_kernel<<<TPB, 256, 0, stream>>>(
        x, Wq, Wk, Wv, bq, bk, bv, qvb, kb, tgt, cnt);
    scan1_kernel<<<SCAN_B, 256, 0, stream>>>(cnt, off, bsum);
    scan23_kernel<<<SCAN_B, 256, 0, stream>>>(bsum, off, cursor);
    fill_kernel<<<edge_blocks, 256, 0, stream>>>(tgt, src, cursor, edge_src);
    attn_kernel<<<(NN + 1) / 2, 256, 0, stream>>>(off, edge_src, qvb, kb, aggb);
    outproj_mfma_kernel<<<TPB, 256, 0, stream>>>(aggb, Wo, bo, (float*)d_out);
}